// Round 4
// baseline (2830.896 us; speedup 1.0000x reference)
//
#include <hip/hip_runtime.h>

// Persistent pipelined 2-layer LSTM for MI355X (gfx950).
// R13: R12 dataflow + single-sync window + h-wave setprio + split acc chains.
//  - 256 WGs x 512 threads; blocks 0..127 layer 0, 128..255 layer 1.
//  - waves: ntile = wave>>2 (batch 16-tile), r = wave&3:
//      r 0,1 -> h-waves (K-halves of recurrent part; r1 runs the epilogue),
//      r 2,3 -> x-waves (K-halves of the x-part, into LDS xbuf dbuf).
//  - slot layout (TRANSPOSED): [producer p=0..127][batch b=0..31] x 16B
//    granule = 8 h-columns (p*8..p*8+7) of one batch, written by exactly ONE
//    producer 16B store-pair. Consumer MFMA B-frag == one granule:
//    p = sub*64 + (lane>>4) + ch*4, addr = slot + (p*32+bb)*16, ch-stride 2KB.
//  - sentinel: host pre-fills slots 1..512 with 0xFF (dword 0xFFFFFFFF = two
//    bf16 -NaNs, unreachable for published h). Slot 0 zero-filled (h0 valid).
//    Validity checked PER DWORD (max4 == ~0u) -> tearing-safe.
//  - consumer poll: 16x global_load_dwordx4 (sc0 sc1 on retries), one
//    vmcnt(0), sched_barrier, check, retry. h-waves coherent-first; L1
//    x-waves plain-first (late consumers; valid-once L2 fills are final).
//  - producer: 2 agent u64 stores, fire-and-forget. No drains/flags.
//  - R13 window structure: ONE __syncthreads per window (mid-sync only).
//    Orderings: xbuf[(w-1)&1] written before writer reached mid-sync(w),
//    read after mid-sync(w); overwrite of that buffer (w+2) is after
//    mid-sync(w+2) which needs the reader's arrival. red is double-buffered
//    (red[w&1]) so r0's re-write at w+2 is ordered by mid-sync(w+1) after
//    r1's read at w. x-wave tails now hide under the next window's poll.
//  - s_setprio: h-waves prio 1, x-waves prio 0 (critical-chain preference).
//  - MFMA: 4 independent accumulator chains (even/odd ch) halve dep depth.
// Bounded retries + abort flag: failure = fast wrong answer, never a hang.

typedef unsigned short ushort_t;
typedef unsigned long long u64_t;
typedef __attribute__((ext_vector_type(8))) short short8;   // 8 bf16 MFMA operand
typedef __attribute__((ext_vector_type(4))) float f32x4;
typedef __attribute__((ext_vector_type(4))) unsigned uint4v;

#define NWG       256
#define NTHREADS  512
#define SEQ       512
#define HSLOT     32768        // 32*1024 elements per time slot (64 KB)
#define FULLSLOTS 513
#define ABORT_U32 8128         // one global abort word (u32 index in cnt)
#define CNT_BYTES 32768
#define POLL_MAX  6000         // retries (~RT each) then abort -> fast fail

__device__ __forceinline__ ushort_t f2bf(float f) {
  unsigned u = __builtin_bit_cast(unsigned, f);
  u += 0x7FFFu + ((u >> 16) & 1u);      // round-to-nearest-even
  return (ushort_t)(u >> 16);
}

__device__ __forceinline__ short8 pack_bf8(f32x4 a, f32x4 b) {
  short8 r;
  r[0] = (short)f2bf(a[0]); r[1] = (short)f2bf(a[1]);
  r[2] = (short)f2bf(a[2]); r[3] = (short)f2bf(a[3]);
  r[4] = (short)f2bf(b[0]); r[5] = (short)f2bf(b[1]);
  r[6] = (short)f2bf(b[2]); r[7] = (short)f2bf(b[3]);
  return r;
}

__device__ __forceinline__ float sigm(float x) { return 1.0f / (1.0f + __expf(-x)); }
__device__ __forceinline__ float fast_tanh(float x) {
  x = fminf(fmaxf(x, -15.f), 15.f);
  float e = __expf(-2.0f * x);
  return (1.0f - e) / (1.0f + e);
}

__device__ __forceinline__ unsigned aload(const unsigned* p) {
  return __hip_atomic_load(p, __ATOMIC_RELAXED, __HIP_MEMORY_SCOPE_AGENT);
}

// Issue 16 granule loads (ch-stride 2 KB), single vmcnt(0), fence scheduling.
// COH: sc0 sc1 -> bypass L1/L2, service at LLC (needed for retry freshness).
template<bool COH>
__device__ __forceinline__ void load16g(f32x4* hv, const char* base) {
#pragma unroll
  for (int ch = 0; ch < 16; ++ch) {
    const char* a = base + (long)ch * 2048;
    if constexpr (COH)
      asm volatile("global_load_dwordx4 %0, %1, off sc0 sc1"
                   : "=v"(hv[ch]) : "v"(a));
    else
      asm volatile("global_load_dwordx4 %0, %1, off"
                   : "=v"(hv[ch]) : "v"(a));
  }
  asm volatile("s_waitcnt vmcnt(0)" ::: "memory");
  __builtin_amdgcn_sched_barrier(0);    // rule #18: pin uses after the wait
}

// Per-dword sentinel check over 16 granules: bad iff any dword == 0xFFFFFFFF.
__device__ __forceinline__ int bad16(const f32x4* hv) {
  int bad = 0;
#pragma unroll
  for (int ch = 0; ch < 16; ++ch) {
    uint4v d = __builtin_bit_cast(uint4v, hv[ch]);
    unsigned m0 = d[0] > d[1] ? d[0] : d[1];
    unsigned m1 = d[2] > d[3] ? d[2] : d[3];
    unsigned m  = m0 > m1 ? m0 : m1;       // v_max3 + v_max
    bad |= (int)(m == 0xFFFFFFFFu);
  }
  return bad;
}

// Poll one wave's 16 granules until all valid. FIRSTCOH: first attempt
// coherent (early consumers) vs plain-cached (late consumers; lets L2 share
// valid fills across the XCD — correct since granules are write-once).
template<bool FIRSTCOH>
__device__ __forceinline__ void poll16(f32x4* hv, const char* base,
                                       unsigned* abortp) {
  load16g<FIRSTCOH>(hv, base);
  if (!__any(bad16(hv))) return;
  for (int it = 0;; ++it) {
    load16g<true>(hv, base);
    if (!__any(bad16(hv))) return;
    if ((it & 63) == 63 && aload(abortp) != 0) return;
    if (it >= POLL_MAX) {
      __hip_atomic_store(abortp, 1u, __ATOMIC_RELAXED, __HIP_MEMORY_SCOPE_AGENT);
      return;
    }
    if (it > 8) __builtin_amdgcn_s_sleep(2);   // ~128 cy backoff
  }
}

// One layer: 513 windows (w=0..512).
//   window w: h-waves run step t=w-1 (w>=1); x-waves compute x-part of step
//   s=w (s<SEQ) into xbuf[s&1] AFTER the mid sync.
// MFMA 16x16x32: A row m: gate=m&3, unit=ub+mt*4+(m>>2).
// C/D: col = lane&15 (=batch), row = (lane>>4)*4 + reg -> reg = gate.
template<int KX, bool XFP32, bool ISL1>
__device__ __forceinline__ void run_layer(
    const void* xsrc, long x_step, long x_bstride,
    const ushort_t* __restrict__ hbuf, ushort_t* __restrict__ hbuf_w,
    const float* __restrict__ W, int ldw,
    const float* __restrict__ bias,
    float* __restrict__ out, int out_h_off, int out_c_off, int write_last,
    float* xbuf, float* red, unsigned* abortp, int ub)
{
  constexpr int XCH = (KX / 2) / 32;                // x chunks per x-wave
  const int lane  = threadIdx.x & 63;
  const int wave  = threadIdx.x >> 6;               // 0..7
  const int ntile = wave >> 2;                      // 0,1
  const int r     = wave & 3;                       // 0,1: h-waves; 2,3: x-waves
  const bool isH  = r < 2;
  const int sub   = r & 1;
  const int wrow  = lane & 15;
  const int kg    = lane >> 4;                      // frag k-group (0..3)
  const int koff  = kg * 8;                         // frag k offset (elements)
  const int bb    = ntile * 16 + (lane & 15);       // batch

  // critical-chain preference: h-waves above x-waves on the shared SIMDs
  if (isH) __builtin_amdgcn_s_setprio(1);

  // ---- pin weight fragments (bf16), 2 M-tiles per wave ----
  const int kbase = isH ? (KX + sub * 512) : ((r - 2) * (KX / 2));
  const int mych  = isH ? 16 : XCH;
  short8 wreg[2][16];
  #pragma unroll
  for (int mt = 0; mt < 2; ++mt) {
    const int grow = (wrow & 3) * 1024 + ub + mt * 4 + (wrow >> 2);
    const float* ws = W + (long)grow * ldw + kbase + koff;
    #pragma unroll
    for (int ch = 0; ch < 16; ++ch) {
      if (ch < mych) {
        f32x4 v0 = *(const f32x4*)(ws + ch * 32);
        f32x4 v1 = *(const f32x4*)(ws + ch * 32 + 4);
        wreg[mt][ch] = pack_bf8(v0, v1);
      }
    }
  }

  const int u0 = ub + kg;
  float bI[2], bF[2], bG[2], bO[2], c[2] = {0.f, 0.f};
  #pragma unroll
  for (int mt = 0; mt < 2; ++mt) {
    const int u = u0 + mt * 4;
    bI[mt] = bias[u];        bF[mt] = bias[1024 + u];
    bG[mt] = bias[2048 + u]; bO[mt] = bias[3072 + u];
  }

  for (int w = 0; w <= SEQ; ++w) {
    const int t = w - 1;
    f32x4 acc[2] = {{0.f,0.f,0.f,0.f},{0.f,0.f,0.f,0.f}};

    if (isH && w >= 1) {
      // h K-half: poll 16 granules (one per MFMA), then 32 MFMAs (2 M-tiles)
      // in 4 independent accumulator chains (even/odd ch) to halve dep depth.
      const char* gb = (const char*)hbuf + (long)t * (HSLOT * 2)
                     + (long)(((sub * 64 + kg) * 32 + bb) * 16);
      f32x4 hv[16];
      poll16<true>(hv, gb, abortp);
      f32x4 accB[2] = {{0.f,0.f,0.f,0.f},{0.f,0.f,0.f,0.f}};
      #pragma unroll
      for (int ch = 0; ch < 16; ch += 2) {
        short8 b0 = __builtin_bit_cast(short8, hv[ch]);
        short8 b1 = __builtin_bit_cast(short8, hv[ch + 1]);
        acc[0]  = __builtin_amdgcn_mfma_f32_16x16x32_bf16(wreg[0][ch],   b0, acc[0], 0, 0, 0);
        acc[1]  = __builtin_amdgcn_mfma_f32_16x16x32_bf16(wreg[1][ch],   b0, acc[1], 0, 0, 0);
        accB[0] = __builtin_amdgcn_mfma_f32_16x16x32_bf16(wreg[0][ch+1], b1, accB[0], 0, 0, 0);
        accB[1] = __builtin_amdgcn_mfma_f32_16x16x32_bf16(wreg[1][ch+1], b1, accB[1], 0, 0, 0);
      }
      acc[0] += accB[0];
      acc[1] += accB[1];
      if (sub == 0) {
        #pragma unroll
        for (int mt = 0; mt < 2; ++mt)
          *(f32x4*)&red[(w & 1) * 1024 + ((ntile * 2 + mt) * 64 + lane) * 4] = acc[mt];
      }
    }

    __syncthreads();   // the ONLY sync per window: red[w&1] + xbuf[(w-1)&1] ready

    if (isH && sub == 1 && w >= 1) {
      // ---- epilogue (both M-tiles) ----
      u64_t pk[2]; float hh[2];
      #pragma unroll
      for (int mt = 0; mt < 2; ++mt) {
        f32x4 a = acc[mt];
        a += *(const f32x4*)&red[(w & 1) * 1024 + ((ntile * 2 + mt) * 64 + lane) * 4];
        a += *(const f32x4*)&xbuf[(((((t & 1) * 2 + ntile) * 2 + 0) * 2 + mt) * 64 + lane) * 4];
        a += *(const f32x4*)&xbuf[(((((t & 1) * 2 + ntile) * 2 + 1) * 2 + mt) * 64 + lane) * 4];
        float pi = a[0] + bI[mt], pf = a[1] + bF[mt];
        float pg = a[2] + bG[mt], po = a[3] + bO[mt];
        float ig = sigm(pi), fg = sigm(pf), gg = fast_tanh(pg), og = sigm(po);
        c[mt] = fg * c[mt] + ig * gg;
        float h = og * fast_tanh(c[mt]);
        hh[mt] = h;
        unsigned v  = f2bf(h);
        unsigned v1 = __shfl((int)v, (lane & 15) + 16);
        unsigned v2 = __shfl((int)v, (lane & 15) + 32);
        unsigned v3 = __shfl((int)v, (lane & 15) + 48);
        pk[mt] = (u64_t)(v & 0xFFFFu) | ((u64_t)(v1 & 0xFFFFu) << 16)
               | ((u64_t)(v2 & 0xFFFFu) << 32) | ((u64_t)(v3 & 0xFFFFu) << 48);
      }
      if (t == SEQ - 1) {
        #pragma unroll
        for (int mt = 0; mt < 2; ++mt) {
          const int u = u0 + mt * 4;
          out[out_h_off + bb * 1024 + u] = hh[mt];
          out[out_c_off + bb * 1024 + u] = c[mt];
          if (write_last) out[bb * 1024 + u] = hh[mt];
        }
      }
      if (lane < 16) {
        // transposed granule: (p = ub>>3, bb) -> 16B, fire-and-forget
        u64_t* dst = (u64_t*)((char*)hbuf_w + (long)(t + 1) * (HSLOT * 2)
                              + (long)((((ub >> 3) * 32 + bb)) * 16));
        __hip_atomic_store(dst,     pk[0], __ATOMIC_RELAXED, __HIP_MEMORY_SCOPE_AGENT);
        __hip_atomic_store(dst + 1, pk[1], __ATOMIC_RELAXED, __HIP_MEMORY_SCOPE_AGENT);
      }
      // no drain: consumers self-synchronize on the data
    }

    if (!isH && w < SEQ) {
      // ---- x-part for step s=w (tail hides under next window's poll) ----
      const int s = w;
      f32x4 xa[2]  = {{0.f,0.f,0.f,0.f},{0.f,0.f,0.f,0.f}};
      f32x4 xaB[2] = {{0.f,0.f,0.f,0.f},{0.f,0.f,0.f,0.f}};
      if constexpr (XFP32) {
        const float* bp = (const float*)xsrc + (long)s * x_step
                          + (long)bb * x_bstride + kbase + koff;
        f32x4 xv[2 * XCH];
        #pragma unroll
        for (int ch = 0; ch < XCH; ++ch) {
          xv[2*ch]   = *(const f32x4*)(bp + ch * 32);
          xv[2*ch+1] = *(const f32x4*)(bp + ch * 32 + 4);
        }
        #pragma unroll
        for (int ch = 0; ch < XCH; ch += 2) {
          short8 bf0 = pack_bf8(xv[2*ch],   xv[2*ch+1]);
          short8 bf1 = pack_bf8(xv[2*ch+2], xv[2*ch+3]);
          xa[0]  = __builtin_amdgcn_mfma_f32_16x16x32_bf16(wreg[0][ch],   bf0, xa[0], 0, 0, 0);
          xa[1]  = __builtin_amdgcn_mfma_f32_16x16x32_bf16(wreg[1][ch],   bf0, xa[1], 0, 0, 0);
          xaB[0] = __builtin_amdgcn_mfma_f32_16x16x32_bf16(wreg[0][ch+1], bf1, xaB[0], 0, 0, 0);
          xaB[1] = __builtin_amdgcn_mfma_f32_16x16x32_bf16(wreg[1][ch+1], bf1, xaB[1], 0, 0, 0);
        }
      } else {
        // L1 x = O0 slot s+1 (xsrc pre-shifted by one slot): sentinel-polled,
        // plain-first (late consumer -> valid L2 fills shared across XCD).
        const char* gb = (const char*)xsrc + (long)s * (HSLOT * 2)
                       + (long)((((r - 2) * 64 + kg) * 32 + bb) * 16);
        f32x4 xv[16];
        poll16<false>(xv, gb, abortp);
        #pragma unroll
        for (int ch = 0; ch < 16; ch += 2) {
          short8 b0 = __builtin_bit_cast(short8, xv[ch]);
          short8 b1 = __builtin_bit_cast(short8, xv[ch + 1]);
          xa[0]  = __builtin_amdgcn_mfma_f32_16x16x32_bf16(wreg[0][ch],   b0, xa[0], 0, 0, 0);
          xa[1]  = __builtin_amdgcn_mfma_f32_16x16x32_bf16(wreg[1][ch],   b0, xa[1], 0, 0, 0);
          xaB[0] = __builtin_amdgcn_mfma_f32_16x16x32_bf16(wreg[0][ch+1], b1, xaB[0], 0, 0, 0);
          xaB[1] = __builtin_amdgcn_mfma_f32_16x16x32_bf16(wreg[1][ch+1], b1, xaB[1], 0, 0, 0);
        }
      }
      xa[0] += xaB[0];
      xa[1] += xaB[1];
      #pragma unroll
      for (int mt = 0; mt < 2; ++mt)
        *(f32x4*)&xbuf[(((((s & 1) * 2 + ntile) * 2 + (r - 2)) * 2 + mt) * 64 + lane) * 4] = xa[mt];
    }
    // no window-boundary sync (R13): next window's mid-sync provides ordering
  }
}

__global__ __launch_bounds__(NTHREADS, 2)
void lstm_persistent(const float* __restrict__ x,  const float* __restrict__ W0,
                     const float* __restrict__ b0, const float* __restrict__ W1,
                     const float* __restrict__ b1, float* __restrict__ out,
                     unsigned* cnt, ushort_t* O0, ushort_t* H1)
{
  __shared__ float xbuf[4096];   // [buf2][ntile2][xsub2][mt2][64][4] = 16 KB
  __shared__ float red[2048];    // [buf2][ntile2][mt2][64][4] = 8 KB (dbuf)
  const int role = (int)(blockIdx.x >> 7);      // 0: layer0, 1: layer1
  const int ub   = (int)(blockIdx.x & 127) * 8;
  unsigned* abortp = cnt + ABORT_U32;

  if (role == 0) {
    run_layer<512, true, false>(x, 512, 262144,
                                O0, O0, W0, 1536, b0,
                                out, 32768, 98304, 0,
                                xbuf, red, abortp, ub);
  } else {
    // L1 x source: O0 shifted by one slot (window-w x reads O0 slot w+1)
    run_layer<1024, false, true>((const void*)(O0 + HSLOT), HSLOT, 1024,
                                 H1, H1, W1, 2048, b1,
                                 out, 65536, 131072, 1,
                                 xbuf, red, abortp, ub);
  }
}

extern "C" void kernel_launch(void* const* d_in, const int* in_sizes, int n_in,
                              void* d_out, int out_size, void* d_ws, size_t ws_size,
                              hipStream_t stream) {
  (void)in_sizes; (void)n_in; (void)out_size;

  const float* x  = (const float*)d_in[0];
  const float* W0 = (const float*)d_in[1];
  const float* b0 = (const float*)d_in[2];
  const float* W1 = (const float*)d_in[3];
  const float* b1 = (const float*)d_in[4];
  float* out = (float*)d_out;

  // workspace:
  //   [0, 32K)            abort word region
  //   [32K, +513*64KB)    O0: layer-0 h slots (write-once, transposed layout)
  //   [.., +513*64KB)     H1: layer-1 h slots
  const size_t hb_bytes = (size_t)FULLSLOTS * HSLOT * sizeof(ushort_t);
  const size_t need     = CNT_BYTES + 2 * hb_bytes;
  if (ws_size < need) return;  // wrong answer -> absmax signal, not a hang

  unsigned* cnt = (unsigned*)d_ws;
  ushort_t* O0  = (ushort_t*)((char*)d_ws + CNT_BYTES);
  ushort_t* H1  = O0 + (size_t)FULLSLOTS * HSLOT;

  hipMemsetAsync(cnt, 0, CNT_BYTES, stream);
  // slot 0 = zeros (h0 = 0, VALID); slots 1..512 = 0xFF sentinel
  hipMemsetAsync(O0, 0x00, (size_t)HSLOT * 2, stream);
  hipMemsetAsync(O0 + HSLOT, 0xFF, (size_t)(FULLSLOTS - 1) * HSLOT * 2, stream);
  hipMemsetAsync(H1, 0x00, (size_t)HSLOT * 2, stream);
  hipMemsetAsync(H1 + HSLOT, 0xFF, (size_t)(FULLSLOTS - 1) * HSLOT * 2, stream);

  lstm_persistent<<<dim3(NWG), dim3(NTHREADS), 0, stream>>>(
      x, W0, b0, W1, b1, out, cnt, O0, H1);
}

// Round 6
// 2058.358 us; speedup vs baseline: 1.3753x; 1.3753x over previous
//
#include <hip/hip_runtime.h>

// Persistent pipelined 2-layer LSTM for MI355X (gfx950).
// R15: R12 dataflow (known-good, 2328us) + drain-free raw barriers
//      (lgkmcnt-only; publishes/polls ride across) + 4-chain MFMA split.
//  - 256 WGs x 512 threads; blocks 0..127 layer 0, 128..255 layer 1.
//  - waves: ntile = wave>>2 (batch 16-tile), r = wave&3:
//      r 0,1 -> h-waves (K-halves of recurrent part; r1 runs the epilogue),
//      r 2,3 -> x-waves (K-halves of the x-part, into LDS xbuf dbuf).
//  - slot layout (TRANSPOSED): [producer p=0..127][batch b=0..31] x 16B
//    granule = 8 h-columns (p*8..p*8+7) of one batch, written by exactly ONE
//    producer 16B store-pair. Consumer MFMA B-frag == one granule:
//    p = sub*64 + (lane>>4) + ch*4, addr = slot + (p*32+bb)*16, ch-stride 2KB.
//  - sentinel: host pre-fills slots 1..512 with 0xFF (dword 0xFFFFFFFF = two
//    bf16 -NaNs, unreachable for published h). Slot 0 zero-filled (h0 valid).
//    Validity checked PER DWORD (max4 == ~0u) -> tearing-safe.
//  - consumer poll: 16x global_load_dwordx4, one vmcnt(0), sched_barrier,
//    check, retry (sc0 sc1 -> LLC-fresh). h-waves coherent-first; L1 x-waves
//    plain-first (late consumers; valid-once L2 fills are final). Loads are
//    issued AND consumed locally (no in-flight asm regs across barriers —
//    R14's NaN lesson: the compiler can't spill in-flight asm destinations).
//  - producer: 2 agent u64 stores, fire-and-forget. No drains/flags.
//  - R15 barriers: s_waitcnt lgkmcnt(0) + raw s_barrier (+sched_barrier).
//    NO vmcnt drain at barriers: publish stores and poll loads float across.
//    LDS ordering preserved (lgkmcnt + plain LDS ops can't cross the
//    "memory"-clobber asm). Nothing on-device needs global drains: consumers
//    self-synchronize on sentinel data.
//  - MFMA: 4 independent accumulator chains (even/odd ch) halve dep depth
//    (proven numerics-exact in R13).
// Bounded retries + abort flag: failure = fast wrong answer, never a hang.

typedef unsigned short ushort_t;
typedef unsigned long long u64_t;
typedef __attribute__((ext_vector_type(8))) short short8;   // 8 bf16 MFMA operand
typedef __attribute__((ext_vector_type(4))) float f32x4;
typedef __attribute__((ext_vector_type(4))) unsigned uint4v;

#define NWG       256
#define NTHREADS  512
#define SEQ       512
#define HSLOT     32768        // 32*1024 elements per time slot (64 KB)
#define FULLSLOTS 513
#define ABORT_U32 8128         // one global abort word (u32 index in cnt)
#define CNT_BYTES 32768
#define POLL_MAX  6000         // retries (~RT each) then abort -> fast fail

__device__ __forceinline__ ushort_t f2bf(float f) {
  unsigned u = __builtin_bit_cast(unsigned, f);
  u += 0x7FFFu + ((u >> 16) & 1u);      // round-to-nearest-even
  return (ushort_t)(u >> 16);
}

__device__ __forceinline__ short8 pack_bf8(f32x4 a, f32x4 b) {
  short8 r;
  r[0] = (short)f2bf(a[0]); r[1] = (short)f2bf(a[1]);
  r[2] = (short)f2bf(a[2]); r[3] = (short)f2bf(a[3]);
  r[4] = (short)f2bf(b[0]); r[5] = (short)f2bf(b[1]);
  r[6] = (short)f2bf(b[2]); r[7] = (short)f2bf(b[3]);
  return r;
}

__device__ __forceinline__ float sigm(float x) { return 1.0f / (1.0f + __expf(-x)); }
__device__ __forceinline__ float fast_tanh(float x) {
  x = fminf(fmaxf(x, -15.f), 15.f);
  float e = __expf(-2.0f * x);
  return (1.0f - e) / (1.0f + e);
}

__device__ __forceinline__ unsigned aload(const unsigned* p) {
  return __hip_atomic_load(p, __ATOMIC_RELAXED, __HIP_MEMORY_SCOPE_AGENT);
}

// Workgroup barrier WITHOUT vmcnt drain: publish stores / poll loads stay in
// flight across it. LDS ordering via lgkmcnt(0); plain LDS ops cannot cross
// the "memory"-clobber asm; sched_barrier pins codegen around s_barrier.
__device__ __forceinline__ void wg_barrier() {
  asm volatile("s_waitcnt lgkmcnt(0)" ::: "memory");
  __builtin_amdgcn_s_barrier();
  __builtin_amdgcn_sched_barrier(0);
}

// Issue 16 granule loads (ch-stride 2 KB), single vmcnt(0), fence scheduling.
// COH: sc0 sc1 -> bypass L1/L2, service at LLC (needed for retry freshness).
template<bool COH>
__device__ __forceinline__ void load16g(f32x4* hv, const char* base) {
#pragma unroll
  for (int ch = 0; ch < 16; ++ch) {
    const char* a = base + (long)ch * 2048;
    if constexpr (COH)
      asm volatile("global_load_dwordx4 %0, %1, off sc0 sc1"
                   : "=v"(hv[ch]) : "v"(a));
    else
      asm volatile("global_load_dwordx4 %0, %1, off"
                   : "=v"(hv[ch]) : "v"(a));
  }
  asm volatile("s_waitcnt vmcnt(0)" ::: "memory");
  __builtin_amdgcn_sched_barrier(0);    // rule #18: pin uses after the wait
}

// Per-dword sentinel check over 16 granules: bad iff any dword == 0xFFFFFFFF.
__device__ __forceinline__ int bad16(const f32x4* hv) {
  int bad = 0;
#pragma unroll
  for (int ch = 0; ch < 16; ++ch) {
    uint4v d = __builtin_bit_cast(uint4v, hv[ch]);
    unsigned m0 = d[0] > d[1] ? d[0] : d[1];
    unsigned m1 = d[2] > d[3] ? d[2] : d[3];
    unsigned m  = m0 > m1 ? m0 : m1;       // v_max3 + v_max
    bad |= (int)(m == 0xFFFFFFFFu);
  }
  return bad;
}

// Poll one wave's 16 granules until all valid. FIRSTCOH: first attempt
// coherent (early consumers) vs plain-cached (late consumers; lets L2 share
// valid fills across the XCD — correct since granules are write-once).
template<bool FIRSTCOH>
__device__ __forceinline__ void poll16(f32x4* hv, const char* base,
                                       unsigned* abortp) {
  load16g<FIRSTCOH>(hv, base);
  if (!__any(bad16(hv))) return;
  for (int it = 0;; ++it) {
    load16g<true>(hv, base);
    if (!__any(bad16(hv))) return;
    if ((it & 63) == 63 && aload(abortp) != 0) return;
    if (it >= POLL_MAX) {
      __hip_atomic_store(abortp, 1u, __ATOMIC_RELAXED, __HIP_MEMORY_SCOPE_AGENT);
      return;
    }
    if (it > 8) __builtin_amdgcn_s_sleep(2);   // ~128 cy backoff
  }
}

// One layer: 513 windows (w=0..512).
//   window w: h-waves run step t=w-1 (w>=1); x-waves compute x-part of step
//   s=w (s<SEQ) into xbuf[s&1] AFTER the mid sync.
// MFMA 16x16x32: A row m: gate=m&3, unit=ub+mt*4+(m>>2).
// C/D: col = lane&15 (=batch), row = (lane>>4)*4 + reg -> reg = gate.
template<int KX, bool XFP32, bool ISL1>
__device__ __forceinline__ void run_layer(
    const void* xsrc, long x_step, long x_bstride,
    const ushort_t* __restrict__ hbuf, ushort_t* __restrict__ hbuf_w,
    const float* __restrict__ W, int ldw,
    const float* __restrict__ bias,
    float* __restrict__ out, int out_h_off, int out_c_off, int write_last,
    float* xbuf, float* red, unsigned* abortp, int ub)
{
  constexpr int XCH = (KX / 2) / 32;                // x chunks per x-wave
  const int lane  = threadIdx.x & 63;
  const int wave  = threadIdx.x >> 6;               // 0..7
  const int ntile = wave >> 2;                      // 0,1
  const int r     = wave & 3;                       // 0,1: h-waves; 2,3: x-waves
  const bool isH  = r < 2;
  const int sub   = r & 1;
  const int wrow  = lane & 15;
  const int kg    = lane >> 4;                      // frag k-group (0..3)
  const int koff  = kg * 8;                         // frag k offset (elements)
  const int bb    = ntile * 16 + (lane & 15);       // batch

  // ---- pin weight fragments (bf16), 2 M-tiles per wave ----
  const int kbase = isH ? (KX + sub * 512) : ((r - 2) * (KX / 2));
  const int mych  = isH ? 16 : XCH;
  short8 wreg[2][16];
  #pragma unroll
  for (int mt = 0; mt < 2; ++mt) {
    const int grow = (wrow & 3) * 1024 + ub + mt * 4 + (wrow >> 2);
    const float* ws = W + (long)grow * ldw + kbase + koff;
    #pragma unroll
    for (int ch = 0; ch < 16; ++ch) {
      if (ch < mych) {
        f32x4 v0 = *(const f32x4*)(ws + ch * 32);
        f32x4 v1 = *(const f32x4*)(ws + ch * 32 + 4);
        wreg[mt][ch] = pack_bf8(v0, v1);
      }
    }
  }

  const int u0 = ub + kg;
  float bI[2], bF[2], bG[2], bO[2], c[2] = {0.f, 0.f};
  #pragma unroll
  for (int mt = 0; mt < 2; ++mt) {
    const int u = u0 + mt * 4;
    bI[mt] = bias[u];        bF[mt] = bias[1024 + u];
    bG[mt] = bias[2048 + u]; bO[mt] = bias[3072 + u];
  }

  for (int w = 0; w <= SEQ; ++w) {
    const int t = w - 1;
    f32x4 acc[2] = {{0.f,0.f,0.f,0.f},{0.f,0.f,0.f,0.f}};

    if (isH && w >= 1) {
      // h K-half: poll 16 granules (one per MFMA), then 32 MFMAs (2 M-tiles)
      // in 4 independent accumulator chains (even/odd ch) to halve dep depth.
      const char* gb = (const char*)hbuf + (long)t * (HSLOT * 2)
                     + (long)(((sub * 64 + kg) * 32 + bb) * 16);
      f32x4 hv[16];
      poll16<true>(hv, gb, abortp);
      f32x4 accB[2] = {{0.f,0.f,0.f,0.f},{0.f,0.f,0.f,0.f}};
      #pragma unroll
      for (int ch = 0; ch < 16; ch += 2) {
        short8 b0 = __builtin_bit_cast(short8, hv[ch]);
        short8 b1 = __builtin_bit_cast(short8, hv[ch + 1]);
        acc[0]  = __builtin_amdgcn_mfma_f32_16x16x32_bf16(wreg[0][ch],   b0, acc[0], 0, 0, 0);
        acc[1]  = __builtin_amdgcn_mfma_f32_16x16x32_bf16(wreg[1][ch],   b0, acc[1], 0, 0, 0);
        accB[0] = __builtin_amdgcn_mfma_f32_16x16x32_bf16(wreg[0][ch+1], b1, accB[0], 0, 0, 0);
        accB[1] = __builtin_amdgcn_mfma_f32_16x16x32_bf16(wreg[1][ch+1], b1, accB[1], 0, 0, 0);
      }
      acc[0] += accB[0];
      acc[1] += accB[1];
      if (sub == 0) {
        #pragma unroll
        for (int mt = 0; mt < 2; ++mt)
          *(f32x4*)&red[((ntile * 2 + mt) * 64 + lane) * 4] = acc[mt];
      }
    }

    wg_barrier();   // A: red ready; xbuf[t&1] from window t-1 already ready

    if (isH && sub == 1 && w >= 1) {
      // ---- epilogue (both M-tiles) ----
      u64_t pk[2]; float hh[2];
      #pragma unroll
      for (int mt = 0; mt < 2; ++mt) {
        f32x4 a = acc[mt];
        a += *(const f32x4*)&red[((ntile * 2 + mt) * 64 + lane) * 4];
        a += *(const f32x4*)&xbuf[(((((t & 1) * 2 + ntile) * 2 + 0) * 2 + mt) * 64 + lane) * 4];
        a += *(const f32x4*)&xbuf[(((((t & 1) * 2 + ntile) * 2 + 1) * 2 + mt) * 64 + lane) * 4];
        float pi = a[0] + bI[mt], pf = a[1] + bF[mt];
        float pg = a[2] + bG[mt], po = a[3] + bO[mt];
        float ig = sigm(pi), fg = sigm(pf), gg = fast_tanh(pg), og = sigm(po);
        c[mt] = fg * c[mt] + ig * gg;
        float h = og * fast_tanh(c[mt]);
        hh[mt] = h;
        unsigned v  = f2bf(h);
        unsigned v1 = __shfl((int)v, (lane & 15) + 16);
        unsigned v2 = __shfl((int)v, (lane & 15) + 32);
        unsigned v3 = __shfl((int)v, (lane & 15) + 48);
        pk[mt] = (u64_t)(v & 0xFFFFu) | ((u64_t)(v1 & 0xFFFFu) << 16)
               | ((u64_t)(v2 & 0xFFFFu) << 32) | ((u64_t)(v3 & 0xFFFFu) << 48);
      }
      if (t == SEQ - 1) {
        #pragma unroll
        for (int mt = 0; mt < 2; ++mt) {
          const int u = u0 + mt * 4;
          out[out_h_off + bb * 1024 + u] = hh[mt];
          out[out_c_off + bb * 1024 + u] = c[mt];
          if (write_last) out[bb * 1024 + u] = hh[mt];
        }
      }
      if (lane < 16) {
        // transposed granule: (p = ub>>3, bb) -> 16B, fire-and-forget
        u64_t* dst = (u64_t*)((char*)hbuf_w + (long)(t + 1) * (HSLOT * 2)
                              + (long)((((ub >> 3) * 32 + bb)) * 16));
        __hip_atomic_store(dst,     pk[0], __ATOMIC_RELAXED, __HIP_MEMORY_SCOPE_AGENT);
        __hip_atomic_store(dst + 1, pk[1], __ATOMIC_RELAXED, __HIP_MEMORY_SCOPE_AGENT);
      }
      // no drain: consumers self-synchronize on the data
    }

    if (!isH && w < SEQ) {
      // ---- x-part for step s=w (hidden under h-critical path) ----
      const int s = w;
      f32x4 xa[2]  = {{0.f,0.f,0.f,0.f},{0.f,0.f,0.f,0.f}};
      f32x4 xaB[2] = {{0.f,0.f,0.f,0.f},{0.f,0.f,0.f,0.f}};
      if constexpr (XFP32) {
        const float* bp = (const float*)xsrc + (long)s * x_step
                          + (long)bb * x_bstride + kbase + koff;
        f32x4 xv[2 * XCH];
        #pragma unroll
        for (int ch = 0; ch < XCH; ++ch) {
          xv[2*ch]   = *(const f32x4*)(bp + ch * 32);
          xv[2*ch+1] = *(const f32x4*)(bp + ch * 32 + 4);
        }
        #pragma unroll
        for (int ch = 0; ch < XCH; ch += 2) {
          short8 bf0 = pack_bf8(xv[2*ch],   xv[2*ch+1]);
          short8 bf1 = pack_bf8(xv[2*ch+2], xv[2*ch+3]);
          xa[0]  = __builtin_amdgcn_mfma_f32_16x16x32_bf16(wreg[0][ch],   bf0, xa[0], 0, 0, 0);
          xa[1]  = __builtin_amdgcn_mfma_f32_16x16x32_bf16(wreg[1][ch],   bf0, xa[1], 0, 0, 0);
          xaB[0] = __builtin_amdgcn_mfma_f32_16x16x32_bf16(wreg[0][ch+1], bf1, xaB[0], 0, 0, 0);
          xaB[1] = __builtin_amdgcn_mfma_f32_16x16x32_bf16(wreg[1][ch+1], bf1, xaB[1], 0, 0, 0);
        }
      } else {
        // L1 x = O0 slot s+1 (xsrc pre-shifted by one slot): sentinel-polled,
        // plain-first (late consumer -> valid L2 fills shared across XCD).
        const char* gb = (const char*)xsrc + (long)s * (HSLOT * 2)
                       + (long)((((r - 2) * 64 + kg) * 32 + bb) * 16);
        f32x4 xv[16];
        poll16<false>(xv, gb, abortp);
        #pragma unroll
        for (int ch = 0; ch < 16; ch += 2) {
          short8 b0 = __builtin_bit_cast(short8, xv[ch]);
          short8 b1 = __builtin_bit_cast(short8, xv[ch + 1]);
          xa[0]  = __builtin_amdgcn_mfma_f32_16x16x32_bf16(wreg[0][ch],   b0, xa[0], 0, 0, 0);
          xa[1]  = __builtin_amdgcn_mfma_f32_16x16x32_bf16(wreg[1][ch],   b0, xa[1], 0, 0, 0);
          xaB[0] = __builtin_amdgcn_mfma_f32_16x16x32_bf16(wreg[0][ch+1], b1, xaB[0], 0, 0, 0);
          xaB[1] = __builtin_amdgcn_mfma_f32_16x16x32_bf16(wreg[1][ch+1], b1, xaB[1], 0, 0, 0);
        }
      }
      xa[0] += xaB[0];
      xa[1] += xaB[1];
      #pragma unroll
      for (int mt = 0; mt < 2; ++mt)
        *(f32x4*)&xbuf[(((((s & 1) * 2 + ntile) * 2 + (r - 2)) * 2 + mt) * 64 + lane) * 4] = xa[mt];
    }

    wg_barrier();   // window boundary (xbuf/red reuse); no vmcnt drain
  }
}

__global__ __launch_bounds__(NTHREADS, 2)
void lstm_persistent(const float* __restrict__ x,  const float* __restrict__ W0,
                     const float* __restrict__ b0, const float* __restrict__ W1,
                     const float* __restrict__ b1, float* __restrict__ out,
                     unsigned* cnt, ushort_t* O0, ushort_t* H1)
{
  __shared__ float xbuf[4096];   // [buf2][ntile2][xsub2][mt2][64][4] = 16 KB
  __shared__ float red[1024];    // [ntile2][mt2][64][4] = 4 KB
  const int role = (int)(blockIdx.x >> 7);      // 0: layer0, 1: layer1
  const int ub   = (int)(blockIdx.x & 127) * 8;
  unsigned* abortp = cnt + ABORT_U32;

  if (role == 0) {
    run_layer<512, true, false>(x, 512, 262144,
                                O0, O0, W0, 1536, b0,
                                out, 32768, 98304, 0,
                                xbuf, red, abortp, ub);
  } else {
    // L1 x source: O0 shifted by one slot (window-w x reads O0 slot w+1)
    run_layer<1024, false, true>((const void*)(O0 + HSLOT), HSLOT, 1024,
                                 H1, H1, W1, 2048, b1,
                                 out, 65536, 131072, 1,
                                 xbuf, red, abortp, ub);
  }
}

extern "C" void kernel_launch(void* const* d_in, const int* in_sizes, int n_in,
                              void* d_out, int out_size, void* d_ws, size_t ws_size,
                              hipStream_t stream) {
  (void)in_sizes; (void)n_in; (void)out_size;

  const float* x  = (const float*)d_in[0];
  const float* W0 = (const float*)d_in[1];
  const float* b0 = (const float*)d_in[2];
  const float* W1 = (const float*)d_in[3];
  const float* b1 = (const float*)d_in[4];
  float* out = (float*)d_out;

  // workspace:
  //   [0, 32K)            abort word region
  //   [32K, +513*64KB)    O0: layer-0 h slots (write-once, transposed layout)
  //   [.., +513*64KB)     H1: layer-1 h slots
  const size_t hb_bytes = (size_t)FULLSLOTS * HSLOT * sizeof(ushort_t);
  const size_t need     = CNT_BYTES + 2 * hb_bytes;
  if (ws_size < need) return;  // wrong answer -> absmax signal, not a hang

  unsigned* cnt = (unsigned*)d_ws;
  ushort_t* O0  = (ushort_t*)((char*)d_ws + CNT_BYTES);
  ushort_t* H1  = O0 + (size_t)FULLSLOTS * HSLOT;

  hipMemsetAsync(cnt, 0, CNT_BYTES, stream);
  // slot 0 = zeros (h0 = 0, VALID); slots 1..512 = 0xFF sentinel
  hipMemsetAsync(O0, 0x00, (size_t)HSLOT * 2, stream);
  hipMemsetAsync(O0 + HSLOT, 0xFF, (size_t)(FULLSLOTS - 1) * HSLOT * 2, stream);
  hipMemsetAsync(H1, 0x00, (size_t)HSLOT * 2, stream);
  hipMemsetAsync(H1 + HSLOT, 0xFF, (size_t)(FULLSLOTS - 1) * HSLOT * 2, stream);

  lstm_persistent<<<dim3(NWG), dim3(NTHREADS), 0, stream>>>(
      x, W0, b0, W1, b1, out, cnt, O0, H1);
}